// Round 20
// baseline (365.505 us; speedup 1.0000x reference)
//
#include <hip/hip_runtime.h>
#include <hip/hip_bf16.h>

#define B_ 8
#define N_ 4096
#define D_ 512
#define BM 128
#define BK 64
#define NTH 512
#define NT (N_ / BK)

typedef __attribute__((ext_vector_type(8))) short bf16x8;
typedef __attribute__((ext_vector_type(4))) float f32x4;
typedef __attribute__((ext_vector_type(16))) float f32x16;

__device__ __forceinline__ short f2bs(float x) {
  union { __hip_bfloat16 h; short s; } u;
  u.h = __float2bfloat16(x);
  return u.s;
}
__device__ __forceinline__ float bs2f(ushort s) {
  union { unsigned u; float f; } v;
  v.u = ((unsigned)s) << 16;
  return v.f;
}

__device__ __forceinline__ void gld16(const void* g, void* l) {
  __builtin_amdgcn_global_load_lds((const __attribute__((address_space(1))) void*)g,
                                   (__attribute__((address_space(3))) void*)l, 16, 0, 0);
}

// ---------------- kernel 1: fused rnorm + prep (one pass over tgt) ----------
// Tbf2[b][d>>3][n][d&7] = bf16( tgt[b][n][d] / ||tgt[b,n,:]|| )   (normalized)
// Vt2 [b][n>>3][d][n&7] = bf16( tgt[b][n][d] )                    (raw)
__global__ void __launch_bounds__(256) prep_kernel(const float* __restrict__ tgt,
                                                   ushort* __restrict__ Tbf2,
                                                   ushort* __restrict__ Vt2) {
  __shared__ ushort L[32][520];                 // raw bf16 rows, padded stride
  const int id = blockIdx.x;                    // 8b x 128 row-groups
  const int b = id >> 7, rg = id & 127;
  const int n0 = rg * 32;
  const int t = threadIdx.x;
  const int r = t >> 3, q = t & 7;              // row 0..31, lane-in-row 0..7

  const float* src = tgt + ((size_t)b * N_ + n0 + r) * D_;
  ushort* T2 = Tbf2 + (size_t)b * N_ * D_;
  ushort* V2 = Vt2  + (size_t)b * N_ * D_;

  float4 f[8][2];
  float ss = 0.0f;
  #pragma unroll
  for (int c = 0; c < 8; ++c) {
    const float* p = src + (c * 8 + q) * 8;
    f[c][0] = *(const float4*)p;
    f[c][1] = *(const float4*)(p + 4);
    ss += f[c][0].x * f[c][0].x + f[c][0].y * f[c][0].y
        + f[c][0].z * f[c][0].z + f[c][0].w * f[c][0].w
        + f[c][1].x * f[c][1].x + f[c][1].y * f[c][1].y
        + f[c][1].z * f[c][1].z + f[c][1].w * f[c][1].w;
  }
  ss += __shfl_xor(ss, 1, 64);
  ss += __shfl_xor(ss, 2, 64);
  ss += __shfl_xor(ss, 4, 64);
  const float rs = rsqrtf(ss);

  #pragma unroll
  for (int c = 0; c < 8; ++c) {
    const int g2 = c * 8 + q;
    bf16x8 nv, rv;
    nv[0]=f2bs(f[c][0].x*rs); nv[1]=f2bs(f[c][0].y*rs);
    nv[2]=f2bs(f[c][0].z*rs); nv[3]=f2bs(f[c][0].w*rs);
    nv[4]=f2bs(f[c][1].x*rs); nv[5]=f2bs(f[c][1].y*rs);
    nv[6]=f2bs(f[c][1].z*rs); nv[7]=f2bs(f[c][1].w*rs);
    *(bf16x8*)(T2 + ((size_t)g2 * N_ + n0 + r) * 8) = nv;
    rv[0]=f2bs(f[c][0].x); rv[1]=f2bs(f[c][0].y);
    rv[2]=f2bs(f[c][0].z); rv[3]=f2bs(f[c][0].w);
    rv[4]=f2bs(f[c][1].x); rv[5]=f2bs(f[c][1].y);
    rv[6]=f2bs(f[c][1].z); rv[7]=f2bs(f[c][1].w);
    #pragma unroll
    for (int e = 0; e < 8; ++e) L[r][g2 * 8 + e] = (ushort)rv[e];
  }
  __syncthreads();

  #pragma unroll
  for (int c2 = 0; c2 < 8; ++c2) {
    int tau = c2 * 256 + t;
    int ng = tau >> 9, d = tau & 511;
    bf16x8 v;
    #pragma unroll
    for (int j = 0; j < 8; ++j) v[j] = (short)L[ng * 8 + j][d];
    *(bf16x8*)(V2 + ((size_t)(n0 / 8 + ng) * D_ + d) * 8) = v;
  }
}

// ---------------- kernel 2: fused  out = tanh(Xn Xn^T) * tgt ----------------
// r18 skeleton (BM=128) + k-split S: waves (qG 0..3, ks 0..1); each wave does
// all 64 m over half-d (S B-frag LDS reads 512->256 KB/tile). Partials dumped
// per-f as bf16 (ks=1 -> Pp, ks=0 -> Pl, same layout); after bar1, ks=0 waves
// reduce + tanh -> Pl final. PV / staging / epilogue = r18 verbatim.
// LDS = 64+64+16+16 = 160 KB exactly.
__global__ void __launch_bounds__(NTH, 2) fused_kernel(const ushort* __restrict__ Tbf2,
                                                       const ushort* __restrict__ Vt2,
                                                       float* __restrict__ out) {
  __shared__ __align__(16) ushort KV[BK * D_];   // [g 64][m 64][8] norm   64 KB
  __shared__ __align__(16) ushort VT[BK * D_];   // [mh 8][d 512][8] raw   64 KB
  __shared__ __align__(16) ushort Pl[BM * BK];   // [mh 8][q 128][8]       16 KB
  __shared__ __align__(16) ushort Pp[BM * BK];   // partner partials       16 KB

  const int id = blockIdx.x;             // 256 blocks = 1/CU
  const int b  = id & 7;                 // batch -> XCD round-robin
  const int q0 = (id >> 3) * BM;

  const int lane = threadIdx.x & 63;
  const int w    = threadIdx.x >> 6;
  const int ks   = w & 1;                // d-half
  const int qG   = w >> 1;               // 0..3 (32 q-rows each)

  const ushort* Tb2 = Tbf2 + (size_t)b * N_ * D_;  // [d/8][n][8] normalized
  const ushort* Vb2 = Vt2  + (size_t)b * N_ * D_;  // [n/8][d][8] raw

  // Q fragments: 32 rows x 256 d (half) = 64 VGPR
  bf16x8 qf[2][8];
  #pragma unroll
  for (int qs = 0; qs < 2; ++qs) {
    const int row = q0 + qG * 32 + qs * 16 + (lane & 15);
    #pragma unroll
    for (int kk = 0; kk < 8; ++kk) {
      int g = ks * 32 + kk * 4 + (lane >> 4);
      qf[qs][kk] = *(const bf16x8*)(Tb2 + ((size_t)g * N_ + row) * 8);
    }
  }

  f32x16 acc[4][2] = {};                 // wave tile 128q x 64d (d = [w*64,+64))

  // ---- hoisted LDS bases (ushort indices; loop offsets are consts)
  const ushort* kvrd = &KV[ks * 16384 + (lane >> 4) * 512 + (lane & 15) * 8]; // +kk*2048+f*128
  const ushort* pard = &Pl[(lane >> 5) * 1024 + (lane & 31) * 8];  // + kq*2048 + qb*256
  const int pidx = ((lane & 15) >> 3) * 1024
                 + (qG * 32 + (lane >> 4) * 4) * 8 + (lane & 7);   // + f*2048 + qs*128 + j*8
  ushort* PlW = &Pl[pidx];
  ushort* PpW = &Pp[pidx];

  // ---- hoisted staging pointers (advance by constants each tile)
  const ushort* kvsrc = Tb2 + (size_t)(w * 8) * N_ * 8 + (size_t)BK * 8 + lane * 8;
  const ushort* vtsrc = Vb2 + (size_t)(8 + w) * D_ * 8 + lane * 8;

  // prologue: stage tile 0
  #pragma unroll
  for (int i = 0; i < 8; ++i)
    gld16(Tb2 + ((size_t)(w * 8 + i) * N_) * 8 + lane * 8, &KV[(w * 8 + i) * 512]);
  #pragma unroll
  for (int i = 0; i < 8; ++i)
    gld16(Vb2 + (size_t)w * D_ * 8 + i * 512 + lane * 8, &VT[w * 4096 + i * 512]);
  __syncthreads();

  for (int t = 0; t < NT; ++t) {
    // ---- S half-d: f-outer, 8 B-reads + 16 MFMA per f; early bf16 dump
    ushort* W = ks ? PpW : PlW;
    __builtin_amdgcn_s_setprio(1);
    #pragma unroll
    for (int f = 0; f < 4; ++f) {
      f32x4 s0 = {}, s1 = {};
      #pragma unroll
      for (int kk = 0; kk < 8; ++kk) {
        bf16x8 bf = *(const bf16x8*)(kvrd + kk * 2048 + f * 128);
        s0 = __builtin_amdgcn_mfma_f32_16x16x32_bf16(qf[0][kk], bf, s0, 0, 0, 0);
        s1 = __builtin_amdgcn_mfma_f32_16x16x32_bf16(qf[1][kk], bf, s1, 0, 0, 0);
      }
      #pragma unroll
      for (int j = 0; j < 4; ++j) {
        W[f * 2048 + j * 8]       = (ushort)f2bs(s0[j]);
        W[f * 2048 + 128 + j * 8] = (ushort)f2bs(s1[j]);
      }
    }
    __builtin_amdgcn_s_setprio(0);
    __syncthreads();                     // bar1: both partials visible; VT(t) drained

    // ---- reduce + tanh (ks=0 waves): Pl = tanh(Pl_part + Pp_part)
    if (ks == 0) {
      #pragma unroll
      for (int f = 0; f < 4; ++f)
        #pragma unroll
        for (int qs = 0; qs < 2; ++qs)
          #pragma unroll
          for (int j = 0; j < 4; ++j) {
            int o = f * 2048 + qs * 128 + j * 8;
            float s = bs2f(PlW[o]) + bs2f(PpW[o]);
            float e = __builtin_amdgcn_exp2f(s * 2.885390082f);  // e^(2s)
            float tn = 1.0f - 2.0f * __builtin_amdgcn_rcpf(e + 1.0f);
            PlW[o] = (ushort)f2bs(tn);
          }
    }
    __syncthreads();                     // bar2: Pl final visible

    if (t < NT - 1) {                    // stage KV(t+1), lands during PV
      #pragma unroll
      for (int i = 0; i < 8; ++i)
        gld16(kvsrc + (size_t)i * N_ * 8, &KV[(w * 8 + i) * 512]);
      kvsrc += BK * 8;                   // +1 KB
    }

    // ---- out += P * V : 24 reads (imm offsets), 32 MFMA-32x32 per wave
    __builtin_amdgcn_s_setprio(1);
    #pragma unroll
    for (int kq = 0; kq < 4; ++kq) {
      bf16x8 vb0 = *(const bf16x8*)(&VT[(lane >> 5) * 4096 + (w * 64 + (lane & 31)) * 8]
                                    + kq * 8192);
      bf16x8 vb1 = *(const bf16x8*)(&VT[(lane >> 5) * 4096 + (w * 64 + (lane & 31)) * 8]
                                    + kq * 8192 + 256);
      #pragma unroll
      for (int qb = 0; qb < 4; ++qb) {
        bf16x8 pa = *(const bf16x8*)(pard + kq * 2048 + qb * 256);
        acc[qb][0] = __builtin_amdgcn_mfma_f32_32x32x16_bf16(pa, vb0, acc[qb][0], 0, 0, 0);
        acc[qb][1] = __builtin_amdgcn_mfma_f32_32x32x16_bf16(pa, vb1, acc[qb][1], 0, 0, 0);
      }
    }
    __builtin_amdgcn_s_setprio(0);
    __syncthreads();                     // bar3: PV done; KV(t+1) drained; VT free

    if (t < NT - 1) {                    // stage VT(t+1), lands during S(t+1)
      #pragma unroll
      for (int i = 0; i < 8; ++i)
        gld16(vtsrc + i * 512, &VT[w * 4096 + i * 512]);
      vtsrc += 8 * D_ * 8;               // +64 KB
    }
  }

  // ---- write out [128 x 512] fp32; C/D 32x32: row=(reg&3)+8*(reg>>2)+4*(lane>>5)
  {
    float* op = out + (size_t)b * N_ * D_ + (size_t)q0 * D_;
    #pragma unroll
    for (int qb = 0; qb < 4; ++qb)
      #pragma unroll
      for (int ds = 0; ds < 2; ++ds) {
        int d = w * 64 + ds * 32 + (lane & 31);
        #pragma unroll
        for (int reg = 0; reg < 16; ++reg) {
          int row = qb * 32 + (reg & 3) + 8 * (reg >> 2) + 4 * (lane >> 5);
          op[(size_t)row * D_ + d] = acc[qb][ds][reg];
        }
      }
  }
}

extern "C" void kernel_launch(void* const* d_in, const int* in_sizes, int n_in,
                              void* d_out, int out_size, void* d_ws, size_t ws_size,
                              hipStream_t stream) {
  const float* tgt = (const float*)d_in[0];
  float* outp = (float*)d_out;

  ushort* Tbf2 = (ushort*)d_ws;                                   // 32 MB
  ushort* Vt2  = Tbf2 + (size_t)B_ * N_ * D_;                     // 32 MB

  prep_kernel<<<dim3(B_ * 128), dim3(256), 0, stream>>>(tgt, Tbf2, Vt2);
  fused_kernel<<<dim3(B_ * (N_ / BM)), dim3(NTH), 0, stream>>>(Tbf2, Vt2, outp);
}

// Round 21
// 280.233 us; speedup vs baseline: 1.3043x; 1.3043x over previous
//
#include <hip/hip_runtime.h>
#include <hip/hip_bf16.h>

#define B_ 8
#define N_ 4096
#define D_ 512
#define BM 128
#define BK 64
#define NTH 512
#define NT (N_ / BK)

typedef __attribute__((ext_vector_type(8))) short bf16x8;
typedef __attribute__((ext_vector_type(4))) float f32x4;
typedef __attribute__((ext_vector_type(16))) float f32x16;

__device__ __forceinline__ short f2bs(float x) {
  union { __hip_bfloat16 h; short s; } u;
  u.h = __float2bfloat16(x);
  return u.s;
}

__device__ __forceinline__ void gld16(const void* g, void* l) {
  __builtin_amdgcn_global_load_lds((const __attribute__((address_space(1))) void*)g,
                                   (__attribute__((address_space(3))) void*)l, 16, 0, 0);
}

// ---------------- kernel 1: fused rnorm + prep (one pass over tgt) ----------
// Tbf2[b][d>>3][n][d&7] = bf16( tgt[b][n][d] / ||tgt[b,n,:]|| )   (normalized)
// Vt2 [b][n>>3][d][n&7] = bf16( tgt[b][n][d] )                    (raw)
__global__ void __launch_bounds__(256) prep_kernel(const float* __restrict__ tgt,
                                                   ushort* __restrict__ Tbf2,
                                                   ushort* __restrict__ Vt2) {
  __shared__ ushort L[32][520];                 // raw bf16 rows, padded stride
  const int id = blockIdx.x;                    // 8b x 128 row-groups
  const int b = id >> 7, rg = id & 127;
  const int n0 = rg * 32;
  const int t = threadIdx.x;
  const int r = t >> 3, q = t & 7;              // row 0..31, lane-in-row 0..7

  const float* src = tgt + ((size_t)b * N_ + n0 + r) * D_;
  ushort* T2 = Tbf2 + (size_t)b * N_ * D_;
  ushort* V2 = Vt2  + (size_t)b * N_ * D_;

  float4 f[8][2];
  float ss = 0.0f;
  #pragma unroll
  for (int c = 0; c < 8; ++c) {
    const float* p = src + (c * 8 + q) * 8;
    f[c][0] = *(const float4*)p;
    f[c][1] = *(const float4*)(p + 4);
    ss += f[c][0].x * f[c][0].x + f[c][0].y * f[c][0].y
        + f[c][0].z * f[c][0].z + f[c][0].w * f[c][0].w
        + f[c][1].x * f[c][1].x + f[c][1].y * f[c][1].y
        + f[c][1].z * f[c][1].z + f[c][1].w * f[c][1].w;
  }
  ss += __shfl_xor(ss, 1, 64);
  ss += __shfl_xor(ss, 2, 64);
  ss += __shfl_xor(ss, 4, 64);
  const float rs = rsqrtf(ss);

  #pragma unroll
  for (int c = 0; c < 8; ++c) {
    const int g2 = c * 8 + q;
    bf16x8 nv, rv;
    nv[0]=f2bs(f[c][0].x*rs); nv[1]=f2bs(f[c][0].y*rs);
    nv[2]=f2bs(f[c][0].z*rs); nv[3]=f2bs(f[c][0].w*rs);
    nv[4]=f2bs(f[c][1].x*rs); nv[5]=f2bs(f[c][1].y*rs);
    nv[6]=f2bs(f[c][1].z*rs); nv[7]=f2bs(f[c][1].w*rs);
    *(bf16x8*)(T2 + ((size_t)g2 * N_ + n0 + r) * 8) = nv;
    rv[0]=f2bs(f[c][0].x); rv[1]=f2bs(f[c][0].y);
    rv[2]=f2bs(f[c][0].z); rv[3]=f2bs(f[c][0].w);
    rv[4]=f2bs(f[c][1].x); rv[5]=f2bs(f[c][1].y);
    rv[6]=f2bs(f[c][1].z); rv[7]=f2bs(f[c][1].w);
    #pragma unroll
    for (int e = 0; e < 8; ++e) L[r][g2 * 8 + e] = (ushort)rv[e];
  }
  __syncthreads();

  #pragma unroll
  for (int c2 = 0; c2 < 8; ++c2) {
    int tau = c2 * 256 + t;
    int ng = tau >> 9, d = tau & 511;
    bf16x8 v;
    #pragma unroll
    for (int j = 0; j < 8; ++j) v[j] = (short)L[ng * 8 + j][d];
    *(bf16x8*)(V2 + ((size_t)(n0 / 8 + ng) * D_ + d) * 8) = v;
  }
}

// ---------------- kernel 2: fused  out = tanh(Xn Xn^T) * tgt ----------------
// r14 skeleton with BM=128 (fat-Q tile): 256 blocks = 1/CU, 64 tile-phases
// per CU (half of r14) -> per-tile fixed cost amortized 2x.
// S: 16x16x32, grid 8q x 1m (qf 64 VGPR, sacc[4]). PV: 32x32x16, grid 1q x 8d,
// wave owns 128q x 64d (acc[4][2] = 128 AGPR). Same staging/barrier schedule.
__global__ void __launch_bounds__(NTH, 2) fused_kernel(const ushort* __restrict__ Tbf2,
                                                       const ushort* __restrict__ Vt2,
                                                       float* __restrict__ out) {
  __shared__ __align__(16) ushort KV[BK * D_];   // [d/8][m 64][8] norm    64 KB
  __shared__ __align__(16) ushort VT[BK * D_];   // [mh 8][d 512][8] raw   64 KB
  __shared__ __align__(16) ushort Pl[BM * BK];   // [mh 8][q 128][8]       16 KB

  const int id = blockIdx.x;             // 256 blocks = 1/CU
  const int b  = id & 7;                 // batch -> XCD round-robin
  const int q0 = (id >> 3) * BM;

  const int lane = threadIdx.x & 63;
  const int w    = threadIdx.x >> 6;
  const int qG   = w;                    // S grid: 8q x 1m

  const ushort* Tb2 = Tbf2 + (size_t)b * N_ * D_;  // [d/8][n][8] normalized
  const ushort* Vb2 = Vt2  + (size_t)b * N_ * D_;  // [n/8][d][8] raw

  // Q fragments: 16 rows x 512 d = 64 VGPR
  bf16x8 qf[16];
  {
    const int row = q0 + qG * 16 + (lane & 15);
    #pragma unroll
    for (int kk = 0; kk < 16; ++kk) {
      int g = kk * 4 + (lane >> 4);
      qf[kk] = *(const bf16x8*)(Tb2 + ((size_t)g * N_ + row) * 8);
    }
  }

  f32x16 acc[4][2] = {};                 // wave tile 128q x 64d (d = [w*64,+64))

  // ---- hoisted LDS bases (ushort indices; loop offsets are consts)
  const ushort* kvrd = &KV[(lane >> 4) * 512 + (lane & 15) * 8];   // + kk*2048 + f*128
  const ushort* pard = &Pl[(lane >> 5) * 1024 + (lane & 31) * 8];  // + ks*2048 + qb*256
  const ushort* vbrd = &VT[(lane >> 5) * 4096 + (w * 64 + (lane & 31)) * 8]; // + ks*8192 (+256)
  ushort*       plwr = &Pl[((lane & 15) >> 3) * 1024
                           + (qG * 16 + (lane >> 4) * 4) * 8
                           + (lane & 7)];                          // + f*2048 + j*8

  // ---- hoisted staging pointers (advance by constants each tile)
  const ushort* kvsrc = Tb2 + (size_t)(w * 8) * N_ * 8 + (size_t)BK * 8 + lane * 8;
  const ushort* vtsrc = Vb2 + (size_t)(8 + w) * D_ * 8 + lane * 8;

  // prologue: stage tile 0
  #pragma unroll
  for (int i = 0; i < 8; ++i)
    gld16(Tb2 + ((size_t)(w * 8 + i) * N_) * 8 + lane * 8, &KV[(w * 8 + i) * 512]);
  #pragma unroll
  for (int i = 0; i < 8; ++i)
    gld16(Vb2 + (size_t)w * D_ * 8 + i * 512 + lane * 8, &VT[w * 4096 + i * 512]);
  __syncthreads();

  for (int t = 0; t < NT; ++t) {
    // ---- S = Qn * Kn^T : 64 reads (imm offsets), 64 MFMA-16x16 per wave
    f32x4 sacc[4] = {};
    __builtin_amdgcn_s_setprio(1);
    #pragma unroll
    for (int kk = 0; kk < 16; ++kk) {
      #pragma unroll
      for (int f = 0; f < 4; ++f) {
        bf16x8 bf = *(const bf16x8*)(kvrd + kk * 2048 + f * 128);
        sacc[f] = __builtin_amdgcn_mfma_f32_16x16x32_bf16(qf[kk], bf, sacc[f], 0, 0, 0);
      }
    }
    __builtin_amdgcn_s_setprio(0);

    // ---- tanh -> Pl ([mh 8][q 128][8])
    #pragma unroll
    for (int f = 0; f < 4; ++f)
      #pragma unroll
      for (int j = 0; j < 4; ++j) {
        float e = __builtin_amdgcn_exp2f(sacc[f][j] * 2.885390082f);  // e^(2s)
        float tn = 1.0f - 2.0f * __builtin_amdgcn_rcpf(e + 1.0f);
        plwr[f * 2048 + j * 8] = (ushort)f2bs(tn);
      }
    __syncthreads();                     // bar1: Pl visible; VT(t) drained

    if (t < NT - 1) {                    // stage KV(t+1), lands during PV
      #pragma unroll
      for (int i = 0; i < 8; ++i)
        gld16(kvsrc + (size_t)i * N_ * 8, &KV[(w * 8 + i) * 512]);
      kvsrc += BK * 8;                   // +1 KB
    }

    // ---- out += P * V : 24 reads (imm offsets), 32 MFMA-32x32 per wave
    __builtin_amdgcn_s_setprio(1);
    #pragma unroll
    for (int ks = 0; ks < 4; ++ks) {
      bf16x8 vb0 = *(const bf16x8*)(vbrd + ks * 8192);
      bf16x8 vb1 = *(const bf16x8*)(vbrd + ks * 8192 + 256);
      #pragma unroll
      for (int qb = 0; qb < 4; ++qb) {
        bf16x8 pa = *(const bf16x8*)(pard + ks * 2048 + qb * 256);
        acc[qb][0] = __builtin_amdgcn_mfma_f32_32x32x16_bf16(pa, vb0, acc[qb][0], 0, 0, 0);
        acc[qb][1] = __builtin_amdgcn_mfma_f32_32x32x16_bf16(pa, vb1, acc[qb][1], 0, 0, 0);
      }
    }
    __builtin_amdgcn_s_setprio(0);
    __syncthreads();                     // bar2: PV done; KV(t+1) drained; VT free

    if (t < NT - 1) {                    // stage VT(t+1), lands during S(t+1)
      #pragma unroll
      for (int i = 0; i < 8; ++i)
        gld16(vtsrc + i * 512, &VT[w * 4096 + i * 512]);
      vtsrc += 8 * D_ * 8;               // +64 KB
    }
  }

  // ---- write out [128 x 512] fp32; C/D 32x32: row=(reg&3)+8*(reg>>2)+4*(lane>>5)
  {
    float* op = out + (size_t)b * N_ * D_ + (size_t)q0 * D_;
    #pragma unroll
    for (int qb = 0; qb < 4; ++qb)
      #pragma unroll
      for (int ds = 0; ds < 2; ++ds) {
        int d = w * 64 + ds * 32 + (lane & 31);
        #pragma unroll
        for (int reg = 0; reg < 16; ++reg) {
          int row = qb * 32 + (reg & 3) + 8 * (reg >> 2) + 4 * (lane >> 5);
          op[(size_t)row * D_ + d] = acc[qb][ds][reg];
        }
      }
  }
}

extern "C" void kernel_launch(void* const* d_in, const int* in_sizes, int n_in,
                              void* d_out, int out_size, void* d_ws, size_t ws_size,
                              hipStream_t stream) {
  const float* tgt = (const float*)d_in[0];
  float* outp = (float*)d_out;

  ushort* Tbf2 = (ushort*)d_ws;                                   // 32 MB
  ushort* Vt2  = Tbf2 + (size_t)B_ * N_ * D_;                     // 32 MB

  prep_kernel<<<dim3(B_ * 128), dim3(256), 0, stream>>>(tgt, Tbf2, Vt2);
  fused_kernel<<<dim3(B_ * (N_ / BM)), dim3(NTH), 0, stream>>>(Tbf2, Vt2, outp);
}